// Round 1
// baseline (1465.094 us; speedup 1.0000x reference)
//
#include <hip/hip_runtime.h>

typedef unsigned short u16;
typedef u16 u16x4 __attribute__((ext_vector_type(4)));
typedef u16 u16x8 __attribute__((ext_vector_type(8)));
typedef __bf16 bf16x8 __attribute__((ext_vector_type(8)));
typedef float f32x4 __attribute__((ext_vector_type(4)));

#define MFMA16 __builtin_amdgcn_mfma_f32_16x16x32_bf16

#define NTOK 49
#define CCH 384
#define TC 1152
#define NH 12
#define BWIN 4096
#define MROWS (BWIN * NTOK)   // 200704
#define QSCALE 0.17677669529663689f

__device__ __forceinline__ u16 f2bf(float f) {
  unsigned u = __builtin_bit_cast(unsigned, f);
  u += 0x7fffu + ((u >> 16) & 1u);
  return (u16)(u >> 16);
}
__device__ __forceinline__ bf16x8 as_bf(u16x8 u) { return __builtin_bit_cast(bf16x8, u); }
__device__ __forceinline__ f32x4 zf4() { f32x4 z = {0.f, 0.f, 0.f, 0.f}; return z; }

// ---------------- prep: weight transpose->bf16, smask build ----------------
__global__ __launch_bounds__(256) void prep_kernel(
    const float* __restrict__ wq, const float* __restrict__ wp,
    const float* __restrict__ bt, const int* __restrict__ ri,
    const float* __restrict__ mask,
    u16* __restrict__ wqT, u16* __restrict__ wpT, float* __restrict__ smask) {
  int idx = blockIdx.x * 256 + threadIdx.x;
  if (idx < 442368) {                       // wqT[n][k] = wq[k][n]
    int nn = idx / 384, kk = idx % 384;
    wqT[idx] = f2bf(wq[(size_t)kk * 1152 + nn]);
  } else if (idx < 589824) {                // wpT[n][k] = wp[k][n]
    int i2 = idx - 442368;
    int nn = i2 / 384, kk = i2 % 384;
    wpT[i2] = f2bf(wp[(size_t)kk * 384 + nn]);
  } else if (idx < 705072) {                // smask[g][h][n][m]
    int i3 = idx - 589824;
    int g = i3 / 28812;
    int rem = i3 % 28812;
    int h = rem / 2401;
    int nm = rem % 2401;
    smask[i3] = bt[ri[nm] * 12 + h] + mask[g * 2401 + nm];
  }
}

// ---------------- QKV GEMM: [M,384]x[384,1152] -> bf16 qkv -----------------
// 128x128 tile, BK=64, 4 waves (2x2), each wave 64x64 = 4x4 16x16 frags.
__global__ __launch_bounds__(256) void qkv_gemm(
    const float* __restrict__ x, const u16* __restrict__ wqT,
    const float* __restrict__ bqkv, u16* __restrict__ qkvb) {
  __shared__ u16 As[128 * 64];
  __shared__ u16 Bs[128 * 64];
  const int t = threadIdx.x;
  const int l = t & 63, w = t >> 6;
  const int rb = blockIdx.x * 128;
  const int cb = blockIdx.y * 128;

  f32x4 acc[4][4];
#pragma unroll
  for (int mi = 0; mi < 4; ++mi)
#pragma unroll
    for (int ni = 0; ni < 4; ++ni) acc[mi][ni] = zf4();

  const int arow = t >> 4;          // 0..15
  const int acol = (t & 15) * 4;    // fp32 elem col 0..60
  const float* xg = x + (size_t)(rb + arow) * 384 + acol;
  const int brow = t >> 3;          // 0..31
  const int bcol = (t & 7) * 8;     // bf16 elem col
  const u16* bg = wqT + (size_t)(cb + brow) * 384 + bcol;

  const u16* aw = As + (((w >> 1) * 64) + (l & 15)) * 64 + (l >> 4) * 8;
  const u16* bw = Bs + (((w & 1) * 64) + (l & 15)) * 64 + (l >> 4) * 8;

  for (int kt = 0; kt < 6; ++kt) {
    // B stage: global_load_lds, 4 x 4KB
#pragma unroll
    for (int j = 0; j < 4; ++j) {
      __builtin_amdgcn_global_load_lds(
          (const __attribute__((address_space(1))) unsigned int*)(bg + (size_t)j * 32 * 384 + kt * 64),
          (__attribute__((address_space(3))) unsigned int*)(Bs + j * 2048 + t * 8),
          16, 0, 0);
    }
    // A stage: fp32 -> bf16 reg-staged
#pragma unroll
    for (int i = 0; i < 8; ++i) {
      f32x4 v = *(const f32x4*)(xg + (size_t)i * 16 * 384 + kt * 64);
      u16x4 hv;
      hv[0] = f2bf(v[0]); hv[1] = f2bf(v[1]); hv[2] = f2bf(v[2]); hv[3] = f2bf(v[3]);
      *(u16x4*)(As + (arow + i * 16) * 64 + acol) = hv;
    }
    __syncthreads();
#pragma unroll
    for (int ks = 0; ks < 2; ++ks) {
      bf16x8 af[4], bfr[4];
#pragma unroll
      for (int mi = 0; mi < 4; ++mi) af[mi] = *(const bf16x8*)(aw + mi * 1024 + ks * 32);
#pragma unroll
      for (int ni = 0; ni < 4; ++ni) bfr[ni] = *(const bf16x8*)(bw + ni * 1024 + ks * 32);
#pragma unroll
      for (int mi = 0; mi < 4; ++mi)
#pragma unroll
        for (int ni = 0; ni < 4; ++ni)
          acc[mi][ni] = MFMA16(af[mi], bfr[ni], acc[mi][ni], 0, 0, 0);
    }
    __syncthreads();
  }

  // epilogue: +bias, q-scale, bf16 store
  const int wrow = (w >> 1) * 64, wcol = (w & 1) * 64;
#pragma unroll
  for (int ni = 0; ni < 4; ++ni) {
    const int gc = cb + wcol + ni * 16 + (l & 15);
    const float bias = bqkv[gc];
    const float scl = (gc < 384) ? QSCALE : 1.0f;
#pragma unroll
    for (int mi = 0; mi < 4; ++mi) {
#pragma unroll
      for (int r = 0; r < 4; ++r) {
        const int gr = rb + wrow + mi * 16 + (l >> 4) * 4 + r;
        qkvb[(size_t)gr * 1152 + gc] = f2bf((acc[mi][ni][r] + bias) * scl);
      }
    }
  }
}

// ---------------- Attention: per-window, per-head -------------------------
__global__ __launch_bounds__(256) void attn_kernel(
    const u16* __restrict__ qkvb, const float* __restrict__ smask,
    u16* __restrict__ attnb) {
  __shared__ u16 Pl[4][64 * 72];   // P, padded stride 72 elems (144B)
  __shared__ u16 Vl[4][64 * 40];   // V, padded stride 40 elems (80B)
  const int t = threadIdx.x;
  const int l = t & 63, w = t >> 6;
  const int b = blockIdx.x;
  u16* Pw = &Pl[w][0];
  u16* Vw = &Vl[w][0];

  for (int hi = 0; hi < 3; ++hi) {
    const int h = w + hi * 4;
    const u16* base = qkvb + (size_t)b * 49 * 1152 + h * 32 + (l >> 4) * 8;

    // q (A-frag) and k (B-frag) loads: lane -> row l&15, 8 consecutive d
    bf16x8 qa[4], kb[4];
#pragma unroll
    for (int mi = 0; mi < 4; ++mi) {
      const int n = mi * 16 + (l & 15);
      u16x8 z = {0, 0, 0, 0, 0, 0, 0, 0};
      qa[mi] = (n < 49) ? *(const bf16x8*)(base + (size_t)n * 1152) : as_bf(z);
    }
#pragma unroll
    for (int nj = 0; nj < 4; ++nj) {
      const int m = nj * 16 + (l & 15);
      u16x8 z = {0, 0, 0, 0, 0, 0, 0, 0};
      kb[nj] = (m < 49) ? *(const bf16x8*)(base + 384 + (size_t)m * 1152) : as_bf(z);
    }
    // v -> LDS (rows >= 49 zeroed)
#pragma unroll
    for (int i = 0; i < 4; ++i) {
      const int row = i * 16 + (l >> 2);
      const int seg = l & 3;
      u16x8 vv = {0, 0, 0, 0, 0, 0, 0, 0};
      if (row < 49)
        vv = *(const u16x8*)(qkvb + (size_t)(b * 49 + row) * 1152 + 768 + h * 32 + seg * 8);
      *(u16x8*)(Vw + row * 40 + seg * 8) = vv;
    }

    // S = q k^T
    f32x4 s[4][4];
#pragma unroll
    for (int mi = 0; mi < 4; ++mi)
#pragma unroll
      for (int nj = 0; nj < 4; ++nj) s[mi][nj] = MFMA16(qa[mi], kb[nj], zf4(), 0, 0, 0);

    // bias+mask, softmax (rows >= 49 stay 0 -> finite garbage, discarded)
    const float* sm = smask + ((size_t)(b & 3) * 12 + h) * 2401;
#pragma unroll
    for (int mi = 0; mi < 4; ++mi) {
#pragma unroll
      for (int r = 0; r < 4; ++r) {
        const int n = mi * 16 + (l >> 4) * 4 + r;
        if (n < 49) {
#pragma unroll
          for (int nj = 0; nj < 4; ++nj) {
            const int m = nj * 16 + (l & 15);
            s[mi][nj][r] = (m < 49) ? s[mi][nj][r] + sm[n * 49 + m] : -1e30f;
          }
        }
      }
    }
#pragma unroll
    for (int mi = 0; mi < 4; ++mi) {
#pragma unroll
      for (int r = 0; r < 4; ++r) {
        float mx = fmaxf(fmaxf(s[mi][0][r], s[mi][1][r]), fmaxf(s[mi][2][r], s[mi][3][r]));
        mx = fmaxf(mx, __shfl_xor(mx, 1));
        mx = fmaxf(mx, __shfl_xor(mx, 2));
        mx = fmaxf(mx, __shfl_xor(mx, 4));
        mx = fmaxf(mx, __shfl_xor(mx, 8));
        float e0 = 0.f;
#pragma unroll
        for (int nj = 0; nj < 4; ++nj) {
          const float p = __expf(s[mi][nj][r] - mx);
          s[mi][nj][r] = p;
          e0 += p;
        }
        e0 += __shfl_xor(e0, 1);
        e0 += __shfl_xor(e0, 2);
        e0 += __shfl_xor(e0, 4);
        e0 += __shfl_xor(e0, 8);
        const float inv = 1.0f / e0;
#pragma unroll
        for (int nj = 0; nj < 4; ++nj) s[mi][nj][r] *= inv;
      }
    }
    // P -> LDS bf16
#pragma unroll
    for (int mi = 0; mi < 4; ++mi)
#pragma unroll
      for (int r = 0; r < 4; ++r) {
        const int row = mi * 16 + (l >> 4) * 4 + r;
#pragma unroll
        for (int nj = 0; nj < 4; ++nj)
          Pw[row * 72 + nj * 16 + (l & 15)] = f2bf(s[mi][nj][r]);
      }
    __syncthreads();

    // out = P @ V
    f32x4 o[4][2];
#pragma unroll
    for (int mi = 0; mi < 4; ++mi) { o[mi][0] = zf4(); o[mi][1] = zf4(); }
#pragma unroll
    for (int ks = 0; ks < 2; ++ks) {
      bf16x8 pa[4];
#pragma unroll
      for (int mi = 0; mi < 4; ++mi)
        pa[mi] = *(const bf16x8*)(Pw + (mi * 16 + (l & 15)) * 72 + ks * 32 + (l >> 4) * 8);
#pragma unroll
      for (int dj = 0; dj < 2; ++dj) {
        u16x8 vb;
#pragma unroll
        for (int jj = 0; jj < 8; ++jj)
          vb[jj] = Vw[(ks * 32 + (l >> 4) * 8 + jj) * 40 + dj * 16 + (l & 15)];
        const bf16x8 vbb = as_bf(vb);
#pragma unroll
        for (int mi = 0; mi < 4; ++mi) o[mi][dj] = MFMA16(pa[mi], vbb, o[mi][dj], 0, 0, 0);
      }
    }
    // store attn_out bf16
#pragma unroll
    for (int mi = 0; mi < 4; ++mi)
#pragma unroll
      for (int dj = 0; dj < 2; ++dj)
#pragma unroll
        for (int r = 0; r < 4; ++r) {
          const int n = mi * 16 + (l >> 4) * 4 + r;
          if (n < 49)
            attnb[(size_t)(b * 49 + n) * 384 + h * 32 + dj * 16 + (l & 15)] = f2bf(o[mi][dj][r]);
        }
    __syncthreads();
  }
}

// ---------------- Proj GEMM: [M,384]x[384,384] -> fp32 out -----------------
__global__ __launch_bounds__(256) void proj_gemm(
    const u16* __restrict__ attnb, const u16* __restrict__ wpT,
    const float* __restrict__ bproj, float* __restrict__ out) {
  __shared__ u16 As[128 * 64];
  __shared__ u16 Bs[128 * 64];
  const int t = threadIdx.x;
  const int l = t & 63, w = t >> 6;
  const int rb = blockIdx.x * 128;
  const int cb = blockIdx.y * 128;

  f32x4 acc[4][4];
#pragma unroll
  for (int mi = 0; mi < 4; ++mi)
#pragma unroll
    for (int ni = 0; ni < 4; ++ni) acc[mi][ni] = zf4();

  const int srow = t >> 3;        // 0..31
  const int scol = (t & 7) * 8;
  const u16* ag = attnb + (size_t)(rb + srow) * 384 + scol;
  const u16* bg = wpT + (size_t)(cb + srow) * 384 + scol;

  const u16* aw = As + (((w >> 1) * 64) + (l & 15)) * 64 + (l >> 4) * 8;
  const u16* bw = Bs + (((w & 1) * 64) + (l & 15)) * 64 + (l >> 4) * 8;

  for (int kt = 0; kt < 6; ++kt) {
#pragma unroll
    for (int j = 0; j < 4; ++j) {
      __builtin_amdgcn_global_load_lds(
          (const __attribute__((address_space(1))) unsigned int*)(ag + (size_t)j * 32 * 384 + kt * 64),
          (__attribute__((address_space(3))) unsigned int*)(As + j * 2048 + t * 8),
          16, 0, 0);
      __builtin_amdgcn_global_load_lds(
          (const __attribute__((address_space(1))) unsigned int*)(bg + (size_t)j * 32 * 384 + kt * 64),
          (__attribute__((address_space(3))) unsigned int*)(Bs + j * 2048 + t * 8),
          16, 0, 0);
    }
    __syncthreads();
#pragma unroll
    for (int ks = 0; ks < 2; ++ks) {
      bf16x8 af[4], bfr[4];
#pragma unroll
      for (int mi = 0; mi < 4; ++mi) af[mi] = *(const bf16x8*)(aw + mi * 1024 + ks * 32);
#pragma unroll
      for (int ni = 0; ni < 4; ++ni) bfr[ni] = *(const bf16x8*)(bw + ni * 1024 + ks * 32);
#pragma unroll
      for (int mi = 0; mi < 4; ++mi)
#pragma unroll
        for (int ni = 0; ni < 4; ++ni)
          acc[mi][ni] = MFMA16(af[mi], bfr[ni], acc[mi][ni], 0, 0, 0);
    }
    __syncthreads();
  }

  const int wrow = (w >> 1) * 64, wcol = (w & 1) * 64;
#pragma unroll
  for (int ni = 0; ni < 4; ++ni) {
    const int gc = cb + wcol + ni * 16 + (l & 15);
    const float bias = bproj[gc];
#pragma unroll
    for (int mi = 0; mi < 4; ++mi) {
#pragma unroll
      for (int r = 0; r < 4; ++r) {
        const int gr = rb + wrow + mi * 16 + (l >> 4) * 4 + r;
        out[(size_t)gr * 384 + gc] = acc[mi][ni][r] + bias;
      }
    }
  }
}

extern "C" void kernel_launch(void* const* d_in, const int* in_sizes, int n_in,
                              void* d_out, int out_size, void* d_ws, size_t ws_size,
                              hipStream_t stream) {
  const float* x       = (const float*)d_in[0];
  const float* mask    = (const float*)d_in[1];
  const float* w_qkv   = (const float*)d_in[2];
  const float* b_qkv   = (const float*)d_in[3];
  const float* bias_t  = (const float*)d_in[4];
  const float* w_proj  = (const float*)d_in[5];
  const float* b_proj  = (const float*)d_in[6];
  const int*   rel_idx = (const int*)d_in[7];
  float* out = (float*)d_out;

  char* ws = (char*)d_ws;
  u16*   wqT   = (u16*)ws;                       // 442368 u16
  u16*   wpT   = (u16*)(ws + 884736);            // 147456 u16
  float* smask = (float*)(ws + 1179648);         // 115248 f32
  u16*   qkvb  = (u16*)(ws + 1640640);           // 200704*1152 u16
  u16*   attnb = (u16*)(ws + 464062656);         // 200704*384 u16

  prep_kernel<<<2755, 256, 0, stream>>>(w_qkv, w_proj, bias_t, rel_idx, mask,
                                        wqT, wpT, smask);
  qkv_gemm<<<dim3(1568, 9), 256, 0, stream>>>(x, wqT, b_qkv, qkvb);
  attn_kernel<<<4096, 256, 0, stream>>>(qkvb, smask, attnb);
  proj_gemm<<<dim3(1568, 3), 256, 0, stream>>>(attnb, wpT, b_proj, out);
}

// Round 3
// 944.722 us; speedup vs baseline: 1.5508x; 1.5508x over previous
//
#include <hip/hip_runtime.h>

typedef unsigned short u16;
typedef u16 u16x4 __attribute__((ext_vector_type(4)));
typedef u16 u16x8 __attribute__((ext_vector_type(8)));
typedef __bf16 bf16x8 __attribute__((ext_vector_type(8)));
typedef float f32x4 __attribute__((ext_vector_type(4)));

#define MFMA16 __builtin_amdgcn_mfma_f32_16x16x32_bf16
#define QSCALE 0.17677669529663689f

__device__ __forceinline__ u16 f2bf(float f) {
  unsigned u = __builtin_bit_cast(unsigned, f);
  u += 0x7fffu + ((u >> 16) & 1u);
  return (u16)(u >> 16);
}
__device__ __forceinline__ bf16x8 as_bf(u16x8 u) { return __builtin_bit_cast(bf16x8, u); }
__device__ __forceinline__ f32x4 zf4() { f32x4 z = {0.f, 0.f, 0.f, 0.f}; return z; }

// DPP lane permute (VALU, no LDS pipe). Reductions over the 16-lane row.
template <int CTRL>
__device__ __forceinline__ float dppf(float x) {
  int i = __builtin_bit_cast(int, x);
  int r = __builtin_amdgcn_update_dpp(i, i, CTRL, 0xf, 0xf, false);
  return __builtin_bit_cast(float, r);
}
__device__ __forceinline__ float rmax16(float x) {
  x = fmaxf(x, dppf<0xB1>(x));    // quad_perm xor1
  x = fmaxf(x, dppf<0x4E>(x));    // quad_perm xor2
  x = fmaxf(x, dppf<0x124>(x));   // row_ror:4
  x = fmaxf(x, dppf<0x128>(x));   // row_ror:8
  return x;
}
__device__ __forceinline__ float rsum16(float x) {
  x += dppf<0xB1>(x);
  x += dppf<0x4E>(x);
  x += dppf<0x124>(x);
  x += dppf<0x128>(x);
  return x;
}

// ---------------- prep: weight transpose->bf16, smask build ----------------
__global__ __launch_bounds__(256) void prep_kernel(
    const float* __restrict__ wq, const float* __restrict__ wp,
    const float* __restrict__ bt, const int* __restrict__ ri,
    const float* __restrict__ mask,
    u16* __restrict__ wqT, u16* __restrict__ wpT, float* __restrict__ smask) {
  int idx = blockIdx.x * 256 + threadIdx.x;
  if (idx < 442368) {                       // wqT[n][k] = wq[k][n]
    int nn = idx / 384, kk = idx % 384;
    wqT[idx] = f2bf(wq[(size_t)kk * 1152 + nn]);
  } else if (idx < 589824) {                // wpT[n][k] = wp[k][n]
    int i2 = idx - 442368;
    int nn = i2 / 384, kk = i2 % 384;
    wpT[i2] = f2bf(wp[(size_t)kk * 384 + nn]);
  } else if (idx < 705072) {                // smask[g][h][n][m]
    int i3 = idx - 589824;
    int g = i3 / 28812;
    int rem = i3 % 28812;
    int h = rem / 2401;
    int nm = rem % 2401;
    smask[i3] = bt[ri[nm] * 12 + h] + mask[g * 2401 + nm];
  }
}

// ---------------- conv_x: fp32 x -> bf16 (one pass) ------------------------
__global__ __launch_bounds__(256) void conv_x(const float* __restrict__ x,
                                              u16* __restrict__ xb) {
  size_t i = ((size_t)blockIdx.x * 256 + threadIdx.x) * 8;
  f32x4 a = *(const f32x4*)(x + i);
  f32x4 b = *(const f32x4*)(x + i + 4);
  u16x8 o;
  o[0] = f2bf(a[0]); o[1] = f2bf(a[1]); o[2] = f2bf(a[2]); o[3] = f2bf(a[3]);
  o[4] = f2bf(b[0]); o[5] = f2bf(b[1]); o[6] = f2bf(b[2]); o[7] = f2bf(b[3]);
  *(u16x8*)(xb + i) = o;
}

// ---------------- GEMM: [M,384] x [384, NCOLB*128], bf16 MFMA --------------
// 128x128 tile, BK=64, 4 waves. T2 XOR-swizzled LDS via pre-swizzled
// global_load_lds source; T1 XCD-chunked block mapping.
template <int NCOLB, bool QKV>
__global__ __launch_bounds__(256) void gemm_bf16(
    const u16* __restrict__ A, const u16* __restrict__ B,
    const float* __restrict__ bias, void* __restrict__ outp) {
  __shared__ u16 As[128 * 64];
  __shared__ u16 Bs[128 * 64];
  const int t = threadIdx.x;
  const int l = t & 63, w = t >> 6;

  // XCD-chunked swizzle: 8 XCDs x 196 row-panels, column-fast within panel.
  const int orig = blockIdx.x;
  const int xcd = orig & 7, q = orig >> 3;
  const int by = xcd * 196 + q / NCOLB;
  const int bx = q % NCOLB;
  const int rb = by * 128, cb = bx * 128;

  f32x4 acc[4][4];
#pragma unroll
  for (int mi = 0; mi < 4; ++mi)
#pragma unroll
    for (int ni = 0; ni < 4; ++ni) acc[mi][ni] = zf4();

  // staging: row = j*32 + (t>>3); LDS slot t&7 holds global granule
  // (t&7) ^ (row&7)  (inverse-swizzled source, linear LDS dest)
  const int srow = t >> 3;
  const int sslot = (((t & 7) ^ ((t >> 3) & 7)) * 8);
  const u16* ag = A + (size_t)(rb + srow) * 384 + sslot;
  const u16* bg = B + (size_t)(cb + srow) * 384 + sslot;

  const int rA = (w >> 1) * 64 + (l & 15);
  const int rB = (w & 1) * 64 + (l & 15);
  const int gsel = l >> 4, rx = l & 7;

  for (int kt = 0; kt < 6; ++kt) {
#pragma unroll
    for (int j = 0; j < 4; ++j) {
      __builtin_amdgcn_global_load_lds(
          (const __attribute__((address_space(1))) unsigned int*)(ag + (size_t)j * 32 * 384 + kt * 64),
          (__attribute__((address_space(3))) unsigned int*)(As + j * 2048 + t * 8),
          16, 0, 0);
      __builtin_amdgcn_global_load_lds(
          (const __attribute__((address_space(1))) unsigned int*)(bg + (size_t)j * 32 * 384 + kt * 64),
          (__attribute__((address_space(3))) unsigned int*)(Bs + j * 2048 + t * 8),
          16, 0, 0);
    }
    __syncthreads();
#pragma unroll
    for (int ks = 0; ks < 2; ++ks) {
      const int g0 = ((ks * 4 + gsel) ^ rx) * 8;   // swizzled granule
      bf16x8 af[4], bfr[4];
#pragma unroll
      for (int mi = 0; mi < 4; ++mi) af[mi] = *(const bf16x8*)(As + (rA + mi * 16) * 64 + g0);
#pragma unroll
      for (int ni = 0; ni < 4; ++ni) bfr[ni] = *(const bf16x8*)(Bs + (rB + ni * 16) * 64 + g0);
#pragma unroll
      for (int mi = 0; mi < 4; ++mi)
#pragma unroll
        for (int ni = 0; ni < 4; ++ni)
          acc[mi][ni] = MFMA16(af[mi], bfr[ni], acc[mi][ni], 0, 0, 0);
    }
    __syncthreads();
  }

  const int wrow = (w >> 1) * 64, wcol = (w & 1) * 64;
  const int LDO = NCOLB * 128;
#pragma unroll
  for (int ni = 0; ni < 4; ++ni) {
    const int gc = cb + wcol + ni * 16 + (l & 15);
    const float bv = bias[gc];
#pragma unroll
    for (int mi = 0; mi < 4; ++mi) {
#pragma unroll
      for (int r = 0; r < 4; ++r) {
        const int gr = rb + wrow + mi * 16 + (l >> 4) * 4 + r;
        if constexpr (QKV) {
          const float scl = (gc < 384) ? QSCALE : 1.0f;
          ((u16*)outp)[(size_t)gr * LDO + gc] = f2bf((acc[mi][ni][r] + bv) * scl);
        } else {
          ((float*)outp)[(size_t)gr * LDO + gc] = acc[mi][ni][r] + bv;
        }
      }
    }
  }
}

// ---------------- Attention: per-window, per-head -------------------------
// PV computed as O^T = V^T @ P^T (A = V^T frags from transposed-V LDS,
// B = P^T frags == row-major P b128 reads). No tr_read instructions.
__global__ __launch_bounds__(256) void attn_kernel(
    const u16* __restrict__ qkvb, const float* __restrict__ smask,
    u16* __restrict__ attnb) {
  __shared__ u16 Pl[4][64 * 72];   // P per wave: [n][k], stride 72 u16
  __shared__ u16 Vt[4][2336];      // V^T per wave: [d][k], addr d*72+(d>>3)*8+k
  const int t = threadIdx.x;
  const int l = t & 63, w = t >> 6;
  const int b = blockIdx.x;
  u16* Pw = &Pl[w][0];
  u16* Vw = &Vt[w][0];

  for (int hi = 0; hi < 3; ++hi) {
    const int h = w + hi * 4;
    const u16* base = qkvb + (size_t)b * 49 * 1152 + h * 32 + (l >> 4) * 8;

    // V^T staging: load V[row][sg*8..+8] (zero for row>=49), scatter to [d][k]
#pragma unroll
    for (int i = 0; i < 4; ++i) {
      const int row = i * 16 + (l >> 2);
      const int sg = l & 3;
      u16x8 vv = {0, 0, 0, 0, 0, 0, 0, 0};
      if (row < 49)
        vv = *(const u16x8*)(qkvb + (size_t)(b * 49 + row) * 1152 + 768 + h * 32 + sg * 8);
#pragma unroll
      for (int e = 0; e < 8; ++e) {
        const int d = sg * 8 + e;
        Vw[d * 72 + (d >> 3) * 8 + row] = vv[e];
      }
    }

    // q (A-frag) / k (B-frag) from global
    bf16x8 qa[4], kb[4];
#pragma unroll
    for (int mi = 0; mi < 4; ++mi) {
      const int n = mi * 16 + (l & 15);
      u16x8 z = {0, 0, 0, 0, 0, 0, 0, 0};
      qa[mi] = (n < 49) ? *(const bf16x8*)(base + (size_t)n * 1152) : as_bf(z);
    }
#pragma unroll
    for (int nj = 0; nj < 4; ++nj) {
      const int m = nj * 16 + (l & 15);
      u16x8 z = {0, 0, 0, 0, 0, 0, 0, 0};
      kb[nj] = (m < 49) ? *(const bf16x8*)(base + 384 + (size_t)m * 1152) : as_bf(z);
    }

    // S = q k^T
    f32x4 s[4][4];
    __builtin_amdgcn_s_setprio(1);
#pragma unroll
    for (int mi = 0; mi < 4; ++mi)
#pragma unroll
      for (int nj = 0; nj < 4; ++nj) s[mi][nj] = MFMA16(qa[mi], kb[nj], zf4(), 0, 0, 0);
    __builtin_amdgcn_s_setprio(0);

    // bias + shift mask
    const float* sm = smask + ((size_t)(b & 3) * 12 + h) * 2401;
#pragma unroll
    for (int mi = 0; mi < 4; ++mi) {
#pragma unroll
      for (int r = 0; r < 4; ++r) {
        const int n = mi * 16 + (l >> 4) * 4 + r;
        if (n < 49) {
#pragma unroll
          for (int nj = 0; nj < 4; ++nj) {
            const int m = nj * 16 + (l & 15);
            s[mi][nj][r] = (m < 49) ? s[mi][nj][r] + sm[n * 49 + m] : -1e30f;
          }
        }
      }
    }
    // softmax: per-row reduce over 4 local cols + 16 lanes (DPP, VALU-only)
#pragma unroll
    for (int mi = 0; mi < 4; ++mi) {
#pragma unroll
      for (int r = 0; r < 4; ++r) {
        float mx = fmaxf(fmaxf(s[mi][0][r], s[mi][1][r]), fmaxf(s[mi][2][r], s[mi][3][r]));
        mx = rmax16(mx);
        float e0 = 0.f;
#pragma unroll
        for (int nj = 0; nj < 4; ++nj) {
          const float p = __expf(s[mi][nj][r] - mx);
          s[mi][nj][r] = p;
          e0 += p;
        }
        e0 = rsum16(e0);
        const float inv = 1.0f / e0;
#pragma unroll
        for (int nj = 0; nj < 4; ++nj) s[mi][nj][r] *= inv;
      }
    }
    // P -> LDS bf16 ([n][k], stride 72)
#pragma unroll
    for (int mi = 0; mi < 4; ++mi)
#pragma unroll
      for (int r = 0; r < 4; ++r) {
        const int row = mi * 16 + (l >> 4) * 4 + r;
#pragma unroll
        for (int nj = 0; nj < 4; ++nj)
          Pw[row * 72 + nj * 16 + (l & 15)] = f2bf(s[mi][nj][r]);
      }
    // drain wave-local LDS writes (V^T + P); waves own disjoint regions
    asm volatile("s_waitcnt lgkmcnt(0)" ::: "memory");
    __builtin_amdgcn_sched_barrier(0);

    // O^T[d][n] = sum_k V^T[d][k] P^T[k][n]
    f32x4 ot[2][4];
#pragma unroll
    for (int dj = 0; dj < 2; ++dj)
#pragma unroll
      for (int mi = 0; mi < 4; ++mi) ot[dj][mi] = zf4();
#pragma unroll
    for (int ks = 0; ks < 2; ++ks) {
      bf16x8 va[2], pb[4];
#pragma unroll
      for (int dj = 0; dj < 2; ++dj) {
        const int d0 = dj * 16 + (l & 15);
        va[dj] = *(const bf16x8*)(Vw + d0 * 72 + (d0 >> 3) * 8 + ks * 32 + (l >> 4) * 8);
      }
#pragma unroll
      for (int mi = 0; mi < 4; ++mi)
        pb[mi] = *(const bf16x8*)(Pw + (mi * 16 + (l & 15)) * 72 + ks * 32 + (l >> 4) * 8);
      __builtin_amdgcn_s_setprio(1);
#pragma unroll
      for (int dj = 0; dj < 2; ++dj)
#pragma unroll
        for (int mi = 0; mi < 4; ++mi)
          ot[dj][mi] = MFMA16(va[dj], pb[mi], ot[dj][mi], 0, 0, 0);
      __builtin_amdgcn_s_setprio(0);
    }
    // store: lane holds O^T[d = dj*16+(l>>4)*4+r][n = mi*16+(l&15)]
#pragma unroll
    for (int dj = 0; dj < 2; ++dj)
#pragma unroll
      for (int mi = 0; mi < 4; ++mi) {
        const int n = mi * 16 + (l & 15);
        if (n < 49) {
          u16x4 pk;
          pk[0] = f2bf(ot[dj][mi][0]);
          pk[1] = f2bf(ot[dj][mi][1]);
          pk[2] = f2bf(ot[dj][mi][2]);
          pk[3] = f2bf(ot[dj][mi][3]);
          *(u16x4*)(attnb + (size_t)(b * 49 + n) * 384 + h * 32 + dj * 16 + (l >> 4) * 4) = pk;
        }
      }
    // all LDS reads of this iter retired before next iter overwrites
    asm volatile("s_waitcnt lgkmcnt(0)" ::: "memory");
    __builtin_amdgcn_sched_barrier(0);
  }
}

extern "C" void kernel_launch(void* const* d_in, const int* in_sizes, int n_in,
                              void* d_out, int out_size, void* d_ws, size_t ws_size,
                              hipStream_t stream) {
  const float* x       = (const float*)d_in[0];
  const float* mask    = (const float*)d_in[1];
  const float* w_qkv   = (const float*)d_in[2];
  const float* b_qkv   = (const float*)d_in[3];
  const float* bias_t  = (const float*)d_in[4];
  const float* w_proj  = (const float*)d_in[5];
  const float* b_proj  = (const float*)d_in[6];
  const int*   rel_idx = (const int*)d_in[7];
  float* out = (float*)d_out;

  char* ws = (char*)d_ws;
  u16*   wqT   = (u16*)ws;                       // 442368 u16
  u16*   wpT   = (u16*)(ws + 884736);            // 147456 u16
  float* smask = (float*)(ws + 1179648);         // 115248 f32
  u16*   qkvb  = (u16*)(ws + 1640640);           // 200704*1152 u16
  u16*   xb    = (u16*)(ws + 464062656);         // 200704*384 u16 (aliases attnb)
  u16*   attnb = (u16*)(ws + 464062656);         // xb dead before attn writes

  prep_kernel<<<2755, 256, 0, stream>>>(w_qkv, w_proj, bias_t, rel_idx, mask,
                                        wqT, wpT, smask);
  conv_x<<<37632, 256, 0, stream>>>(x, xb);
  gemm_bf16<9, true><<<14112, 256, 0, stream>>>(xb, wqT, b_qkv, qkvb);
  attn_kernel<<<4096, 256, 0, stream>>>(qkvb, smask, attnb);
  gemm_bf16<3, false><<<4704, 256, 0, stream>>>(attnb, wpT, b_proj, out);
}